// Round 12
// baseline (282.262 us; speedup 1.0000x reference)
//
#include <hip/hip_runtime.h>
#include <cstdint>

#define AS1 __attribute__((address_space(1)))
#define AS3 __attribute__((address_space(3)))

typedef __attribute__((ext_vector_type(8))) short short8;
typedef __attribute__((ext_vector_type(4))) float f32x4;

constexpr int SEQ   = 2048;
constexpr int INSZ  = 256;   // K
constexpr int OUTSZ = 256;

__device__ __forceinline__ ushort f2bf(float f) {
  union { float f; uint32_t u; } v; v.f = f;
  uint32_t u = v.u;
  return (ushort)((u + 0x7FFFu + ((u >> 16) & 1u)) >> 16);  // RNE
}
__device__ __forceinline__ uint32_t pk2(float a, float b) {
  return (uint32_t)f2bf(a) | ((uint32_t)f2bf(b) << 16);
}
__device__ __forceinline__ uint32_t cvtpk(float lo, float hi) {
  uint32_t r;
  asm("v_cvt_pk_bf16_f32 %0, %1, %2" : "=v"(r) : "v"(lo), "v"(hi));
  return r;
}

// ---------------------------------------------------------------------------
// Kernel 1: W_b = U[idx[b]] @ V, bf16, stored in MFMA B-fragment order:
//   ushort index = b*65536 + k5*8192 + nb*512 + lane*8 + j
// ---------------------------------------------------------------------------
__global__ __launch_bounds__(256) void synth_w(
    const float* __restrict__ U, const float* __restrict__ V,
    const int* __restrict__ idx, ushort* __restrict__ wsW)
{
  const int b   = blockIdx.y;
  const int kb  = blockIdx.x;     // 0..3 -> local k window [kb*64, kb*64+64)
  const int tid = threadIdx.x;
  const int ch  = idx[b];
  const float u0 = U[ch*4+0], u1 = U[ch*4+1], u2 = U[ch*4+2], u3 = U[ch*4+3];

  __shared__ ushort tile[64][260];

  const int o4    = (tid & 63) * 4;
  const int kbase = (tid >> 6) * 16;
  for (int kk = 0; kk < 16; ++kk) {
    const int k  = kbase + kk;
    const int gk = kb*64 + k;
    const float* vp = V + (size_t)gk*OUTSZ + o4;
    float4 a = *(const float4*)(vp);
    float4 c = *(const float4*)(vp + 65536);
    float4 d = *(const float4*)(vp + 131072);
    float4 e = *(const float4*)(vp + 196608);
    ushort4 pkv;
    pkv.x = f2bf(u0*a.x + u1*c.x + u2*d.x + u3*e.x);
    pkv.y = f2bf(u0*a.y + u1*c.y + u2*d.y + u3*e.y);
    pkv.z = f2bf(u0*a.z + u1*c.z + u2*d.z + u3*e.z);
    pkv.w = f2bf(u0*a.w + u1*c.w + u2*d.w + u3*e.w);
    *(ushort4*)(&tile[k][o4]) = pkv;
  }
  __syncthreads();

  for (int s = 0; s < 8; ++s) {
    const int c      = s*256 + tid;
    const int kshalf = c >> 10;
    const int nb     = (c >> 6) & 15;
    const int lane   = c & 63;
    const int o      = nb*16 + (lane & 15);
    const int k0     = kshalf*32 + (lane >> 4)*8;
    uint4 pkv;
    pkv.x = (uint32_t)tile[k0+0][o] | ((uint32_t)tile[k0+1][o] << 16);
    pkv.y = (uint32_t)tile[k0+2][o] | ((uint32_t)tile[k0+3][o] << 16);
    pkv.z = (uint32_t)tile[k0+4][o] | ((uint32_t)tile[k0+5][o] << 16);
    pkv.w = (uint32_t)tile[k0+6][o] | ((uint32_t)tile[k0+7][o] << 16);
    uint4* dst = (uint4*)(wsW + (size_t)b*65536 + (size_t)(2*kb + kshalf)*8192
                              + nb*512 + lane*8);
    *dst = pkv;
  }
}

// ---------------------------------------------------------------------------
// Kernel 2: R10 skeleton + T5 setprio around MFMA cluster + NT cache policy:
// x staged via global_load_lds with aux=2 (NT: don't pollute L2 -> W stays
// L2-resident), out written with nontemporal stores. Depth-3 slab ring,
// counted vmcnt, raw s_barrier, cvt_pk on fragment path, swapped-operand MFMA.
// ---------------------------------------------------------------------------
__global__ __launch_bounds__(256, 4) void lr_gemm(
    const float* __restrict__ x, const int* __restrict__ idx,
    const float* __restrict__ bias, const ushort* __restrict__ wsW,
    float* __restrict__ out)
{
  __shared__ float ldsF[4][64*32];   // 4 slabs x 8 KB = 32768 B

  // XCD-aware swizzle (8192 = 8*1024)
  const int wg  = blockIdx.x;
  const int swz = (wg & 7) * 1024 + (wg >> 3);
  const int b   = swz >> 5;
  const int n0  = (swz & 31) * 64;

  const int tid  = threadIdx.x;
  const int lane = tid & 63;
  const int wave = tid >> 6;      // owns cols [wave*64, wave*64+64)
  const int hi16 = lane >> 4;
  const int lo16 = lane & 15;

  const float*  xb  = x + ((size_t)b*SEQ + n0)*INSZ;
  const ushort* wbp = wsW + (size_t)b*65536 + wave*2048 + lane*8;

  // stage slab S: 16 gload_lds of 1024B; src pre-swizzled so LDS slot
  // (row, c) holds x chunk (row, c ^ (row&7)); dest linear. aux=2 -> NT.
  const int csrc = (lane & 7) ^ (lane >> 3);
#define STAGE(S) do {                                                        \
    _Pragma("unroll")                                                        \
    for (int t = 0; t < 2; ++t) {                                            \
      const int g = wave*2 + t;              /* 8-row group 0..7 */          \
      const int r = g*8 + (lane >> 3);                                       \
      const float* srcp = xb + (size_t)r*INSZ + (S)*32 + csrc*4;             \
      float* dstp = &ldsF[(S) & 3][g*256];                                   \
      __builtin_amdgcn_global_load_lds((const AS1 void*)srcp,                \
                                       (AS3 void*)dstp, 16, 0, 2);           \
    } } while (0)

  STAGE(0); STAGE(1); STAGE(2);
  asm volatile("s_waitcnt vmcnt(4)" ::: "memory");   // slab0 landed
  __builtin_amdgcn_s_barrier();
  __builtin_amdgcn_sched_barrier(0);

  f32x4 acc[4][4] = {};
  const int s0idx = (hi16*2) ^ (lo16 & 7);   // slot of chunk hi16*2
  const int s1idx = s0idx ^ 1;

#define KSTEP(S, WSTR) do {                                                  \
    short8 bf[4], af[4];                                                     \
    _Pragma("unroll")                                                        \
    for (int n = 0; n < 4; ++n)                                              \
      bf[n] = *(const short8*)(wbp + (size_t)(S)*8192 + n*512);              \
    if ((S) < 5) STAGE((S)+3);                                               \
    const float* fb = &ldsF[(S) & 3][0];                                     \
    _Pragma("unroll")                                                        \
    for (int m = 0; m < 4; ++m) {                                            \
      const float* p = fb + (m*16 + lo16)*32;                                \
      float4 fa = *(const float4*)(p + s0idx*4);                             \
      float4 fc = *(const float4*)(p + s1idx*4);                             \
      union { uint32_t u[4]; short8 s8; } pk;                                \
      pk.u[0] = cvtpk(fa.x, fa.y); pk.u[1] = cvtpk(fa.z, fa.w);              \
      pk.u[2] = cvtpk(fc.x, fc.y); pk.u[3] = cvtpk(fc.z, fc.w);              \
      af[m] = pk.s8;                                                         \
    }                                                                        \
    __builtin_amdgcn_s_setprio(1);                                           \
    _Pragma("unroll")                                                        \
    for (int m = 0; m < 4; ++m)                                              \
      _Pragma("unroll")                                                      \
      for (int n = 0; n < 4; ++n)                                            \
        acc[m][n] = __builtin_amdgcn_mfma_f32_16x16x32_bf16(                 \
            bf[n], af[m], acc[m][n], 0, 0, 0);                               \
    __builtin_amdgcn_s_setprio(0);                                           \
    if ((S) < 7) {                                                           \
      __builtin_amdgcn_sched_barrier(0);                                     \
      asm volatile("s_waitcnt vmcnt(" WSTR ")" ::: "memory");                \
      __builtin_amdgcn_s_barrier();                                          \
      __builtin_amdgcn_sched_barrier(0);                                     \
    } } while (0)

  KSTEP(0, "4"); KSTEP(1, "4"); KSTEP(2, "4"); KSTEP(3, "4");
  KSTEP(4, "4"); KSTEP(5, "2"); KSTEP(6, "0"); KSTEP(7, "0");

  // ---- epilogue: swapped layout -> lane holds 4 consecutive out cols; NT stores
  const int ch = idx[b];
  float* outb = out + ((size_t)b*SEQ + n0)*OUTSZ;
  #pragma unroll
  for (int n = 0; n < 4; ++n) {
    const float4 bv4 = *(const float4*)(bias + (size_t)ch*OUTSZ
                                        + wave*64 + n*16 + hi16*4);
    #pragma unroll
    for (int m = 0; m < 4; ++m) {
      f32x4 v;
      v.x = acc[m][n][0] + bv4.x;
      v.y = acc[m][n][1] + bv4.y;
      v.z = acc[m][n][2] + bv4.z;
      v.w = acc[m][n][3] + bv4.w;
      __builtin_nontemporal_store(v,
          (f32x4*)(outb + (size_t)(m*16 + lo16)*OUTSZ + wave*64 + n*16 + hi16*4));
    }
  }
#undef KSTEP
#undef STAGE
}

extern "C" void kernel_launch(void* const* d_in, const int* in_sizes, int n_in,
                              void* d_out, int out_size, void* d_ws, size_t ws_size,
                              hipStream_t stream) {
  const float* x    = (const float*)d_in[0];
  const int*   idx  = (const int*)d_in[1];
  const float* U    = (const float*)d_in[2];
  const float* V    = (const float*)d_in[3];
  const float* bias = (const float*)d_in[4];
  float* out  = (float*)d_out;
  ushort* wsW = (ushort*)d_ws;     // 256*65536*2 = 32 MiB

  synth_w<<<dim3(4, 256), 256, 0, stream>>>(U, V, idx, wsW);
  lr_gemm<<<8192, 256, 0, stream>>>(x, idx, bias, wsW, out);
}

// Round 13
// 260.220 us; speedup vs baseline: 1.0847x; 1.0847x over previous
//
#include <hip/hip_runtime.h>
#include <cstdint>

#define AS1 __attribute__((address_space(1)))
#define AS3 __attribute__((address_space(3)))

typedef __attribute__((ext_vector_type(8))) short short8;
typedef __attribute__((ext_vector_type(4))) float f32x4;

constexpr int SEQ   = 2048;
constexpr int INSZ  = 256;   // K
constexpr int OUTSZ = 256;

__device__ __forceinline__ ushort f2bf(float f) {
  union { float f; uint32_t u; } v; v.f = f;
  uint32_t u = v.u;
  return (ushort)((u + 0x7FFFu + ((u >> 16) & 1u)) >> 16);  // RNE
}
__device__ __forceinline__ uint32_t pk2(float a, float b) {
  return (uint32_t)f2bf(a) | ((uint32_t)f2bf(b) << 16);
}
__device__ __forceinline__ uint32_t cvtpk(float lo, float hi) {
  uint32_t r;
  asm("v_cvt_pk_bf16_f32 %0, %1, %2" : "=v"(r) : "v"(lo), "v"(hi));
  return r;
}

// ---------------------------------------------------------------------------
// Kernel 1: W_b = U[idx[b]] @ V, bf16, stored in MFMA B-fragment order:
//   ushort index = b*65536 + k5*8192 + nb*512 + lane*8 + j
// ---------------------------------------------------------------------------
__global__ __launch_bounds__(256) void synth_w(
    const float* __restrict__ U, const float* __restrict__ V,
    const int* __restrict__ idx, ushort* __restrict__ wsW)
{
  const int b   = blockIdx.y;
  const int kb  = blockIdx.x;
  const int tid = threadIdx.x;
  const int ch  = idx[b];
  const float u0 = U[ch*4+0], u1 = U[ch*4+1], u2 = U[ch*4+2], u3 = U[ch*4+3];

  __shared__ ushort tile[64][260];

  const int o4    = (tid & 63) * 4;
  const int kbase = (tid >> 6) * 16;
  for (int kk = 0; kk < 16; ++kk) {
    const int k  = kbase + kk;
    const int gk = kb*64 + k;
    const float* vp = V + (size_t)gk*OUTSZ + o4;
    float4 a = *(const float4*)(vp);
    float4 c = *(const float4*)(vp + 65536);
    float4 d = *(const float4*)(vp + 131072);
    float4 e = *(const float4*)(vp + 196608);
    ushort4 pkv;
    pkv.x = f2bf(u0*a.x + u1*c.x + u2*d.x + u3*e.x);
    pkv.y = f2bf(u0*a.y + u1*c.y + u2*d.y + u3*e.y);
    pkv.z = f2bf(u0*a.z + u1*c.z + u2*d.z + u3*e.z);
    pkv.w = f2bf(u0*a.w + u1*c.w + u2*d.w + u3*e.w);
    *(ushort4*)(&tile[k][o4]) = pkv;
  }
  __syncthreads();

  for (int s = 0; s < 8; ++s) {
    const int c      = s*256 + tid;
    const int kshalf = c >> 10;
    const int nb     = (c >> 6) & 15;
    const int lane   = c & 63;
    const int o      = nb*16 + (lane & 15);
    const int k0     = kshalf*32 + (lane >> 4)*8;
    uint4 pkv;
    pkv.x = (uint32_t)tile[k0+0][o] | ((uint32_t)tile[k0+1][o] << 16);
    pkv.y = (uint32_t)tile[k0+2][o] | ((uint32_t)tile[k0+3][o] << 16);
    pkv.z = (uint32_t)tile[k0+4][o] | ((uint32_t)tile[k0+5][o] << 16);
    pkv.w = (uint32_t)tile[k0+6][o] | ((uint32_t)tile[k0+7][o] << 16);
    uint4* dst = (uint4*)(wsW + (size_t)b*65536 + (size_t)(2*kb + kshalf)*8192
                              + nb*512 + lane*8);
    *dst = pkv;
  }
}

// ---------------------------------------------------------------------------
// Kernel 2: issue-order-disciplined pipeline. 8 LDS slabs (64KB, no reuse ->
// RAW-only fences). 4 named B-register sets, depth-3 B prefetch. Per-wave
// issue tape is fixed; every fence's vmcnt hand-computed so the newest load
// waited on is >=2 k5-periods old. 2 blocks/CU, 256-VGPR budget.
// ---------------------------------------------------------------------------
__global__ __launch_bounds__(256, 2) void lr_gemm(
    const float* __restrict__ x, const int* __restrict__ idx,
    const float* __restrict__ bias, const ushort* __restrict__ wsW,
    float* __restrict__ out)
{
  __shared__ float ldsF[8][2048];   // 8 slabs x 8 KB = 65536 B

  // XCD-aware swizzle (8192 = 8*1024)
  const int wg  = blockIdx.x;
  const int swz = (wg & 7) * 1024 + (wg >> 3);
  const int b   = swz >> 5;
  const int n0  = (swz & 31) * 64;

  const int tid  = threadIdx.x;
  const int lane = tid & 63;
  const int wave = tid >> 6;      // owns cols [wave*64, wave*64+64)
  const int hi16 = lane >> 4;
  const int lo16 = lane & 15;

  const float*  xb  = x + ((size_t)b*SEQ + n0)*INSZ;
  const ushort* wbp = wsW + (size_t)b*65536 + wave*2048 + lane*8;

  // stage slab S (8KB): 8 x gload_lds of 1024B (2 per wave); src pre-swizzled
  // so LDS slot (row, c) holds x chunk (row, c ^ (row&7)); dest linear.
  const int csrc = (lane & 7) ^ (lane >> 3);
#define STAGE(S) do {                                                        \
    _Pragma("unroll")                                                        \
    for (int t = 0; t < 2; ++t) {                                            \
      const int g = wave*2 + t;              /* 8-row group 0..7 */          \
      const int r = g*8 + (lane >> 3);                                       \
      const float* srcp = xb + (size_t)r*INSZ + (S)*32 + csrc*4;             \
      float* dstp = &ldsF[(S)][g*256];                                       \
      __builtin_amdgcn_global_load_lds((const AS1 void*)srcp,                \
                                       (AS3 void*)dstp, 16, 0, 0);           \
    } } while (0)

#define LOADB(DST, S) do {                                                   \
    _Pragma("unroll")                                                        \
    for (int n = 0; n < 4; ++n)                                              \
      DST[n] = *(const short8*)(wbp + (size_t)(S)*8192 + n*512);             \
    } while (0)

  short8 bfA[4], bfB[4], bfC[4];
  short8 bfD[4];

  // ---- prologue issue tape: bf0,bf1,bf2 then slabs 0..5 (24 loads/wave)
  LOADB(bfA, 0); LOADB(bfB, 1); LOADB(bfC, 2);
  STAGE(0); STAGE(1); STAGE(2); STAGE(3); STAGE(4); STAGE(5);
  // slab0+bf0..2 landed when outstanding <= 10 (st1..st5 remain)
  asm volatile("s_waitcnt vmcnt(10)" ::: "memory");
  __builtin_amdgcn_s_barrier();
  __builtin_amdgcn_sched_barrier(0);

  f32x4 acc[4][4] = {};
  const int s0idx = (hi16*2) ^ (lo16 & 7);
  const int s1idx = s0idx ^ 1;

  // KSTEP(S): [LOADB S+3][STAGE S+6][compute S][fence]
#define KSTEP(S, BCUR, BLD, DO_LB, DO_ST, DO_FENCE, WSTR) do {               \
    if (DO_LB) LOADB(BLD, (S)+3);                                            \
    if (DO_ST) STAGE((S)+6);                                                 \
    short8 af[4];                                                            \
    const float* fb = &ldsF[(S)][0];                                         \
    _Pragma("unroll")                                                        \
    for (int m = 0; m < 4; ++m) {                                            \
      const float* p = fb + (m*16 + lo16)*32;                                \
      float4 fa = *(const float4*)(p + s0idx*4);                             \
      float4 fc = *(const float4*)(p + s1idx*4);                             \
      union { uint32_t u[4]; short8 s8; } pk;                                \
      pk.u[0] = cvtpk(fa.x, fa.y); pk.u[1] = cvtpk(fa.z, fa.w);              \
      pk.u[2] = cvtpk(fc.x, fc.y); pk.u[3] = cvtpk(fc.z, fc.w);              \
      af[m] = pk.s8;                                                         \
    }                                                                        \
    _Pragma("unroll")                                                        \
    for (int m = 0; m < 4; ++m)                                              \
      _Pragma("unroll")                                                      \
      for (int n = 0; n < 4; ++n)                                            \
        acc[m][n] = __builtin_amdgcn_mfma_f32_16x16x32_bf16(                 \
            BCUR[n], af[m], acc[m][n], 0, 0, 0);                             \
    if (DO_FENCE) {                                                          \
      __builtin_amdgcn_sched_barrier(0);                                     \
      asm volatile("s_waitcnt vmcnt(" WSTR ")" ::: "memory");                \
      __builtin_amdgcn_s_barrier();                                          \
      __builtin_amdgcn_sched_barrier(0);                                     \
    } } while (0)

  //        S  cur  ld   lb st  fence  vmcnt (from issue tape; >=2 periods old)
  KSTEP(0, bfA, bfD, 1, 1, 1, "14");
  KSTEP(1, bfB, bfA, 1, 1, 1, "18");
  KSTEP(2, bfC, bfB, 1, 0, 1, "12");
  KSTEP(3, bfD, bfC, 1, 0, 1, "10");
  KSTEP(4, bfA, bfD, 1, 0, 1, "8");
  KSTEP(5, bfB, bfA, 0, 0, 1, "4");
  KSTEP(6, bfC, bfA, 0, 0, 1, "0");
  KSTEP(7, bfD, bfA, 0, 0, 0, "0");

  // ---- epilogue: swapped layout -> lane holds 4 consecutive out cols
  const int ch = idx[b];
  float* outb = out + ((size_t)b*SEQ + n0)*OUTSZ;
  #pragma unroll
  for (int n = 0; n < 4; ++n) {
    const float4 bv4 = *(const float4*)(bias + (size_t)ch*OUTSZ
                                        + wave*64 + n*16 + hi16*4);
    #pragma unroll
    for (int m = 0; m < 4; ++m) {
      float4 v;
      v.x = acc[m][n][0] + bv4.x;
      v.y = acc[m][n][1] + bv4.y;
      v.z = acc[m][n][2] + bv4.z;
      v.w = acc[m][n][3] + bv4.w;
      *(float4*)(outb + (size_t)(m*16 + lo16)*OUTSZ + wave*64 + n*16 + hi16*4) = v;
    }
  }
#undef KSTEP
#undef LOADB
#undef STAGE
}

extern "C" void kernel_launch(void* const* d_in, const int* in_sizes, int n_in,
                              void* d_out, int out_size, void* d_ws, size_t ws_size,
                              hipStream_t stream) {
  const float* x    = (const float*)d_in[0];
  const int*   idx  = (const int*)d_in[1];
  const float* U    = (const float*)d_in[2];
  const float* V    = (const float*)d_in[3];
  const float* bias = (const float*)d_in[4];
  float* out  = (float*)d_out;
  ushort* wsW = (ushort*)d_ws;     // 256*65536*2 = 32 MiB

  synth_w<<<dim3(4, 256), 256, 0, stream>>>(U, V, idx, wsW);
  lr_gemm<<<8192, 256, 0, stream>>>(x, idx, bias, wsW, out);
}